// Round 3
// baseline (542.571 us; speedup 1.0000x reference)
//
#include <hip/hip_runtime.h>
#include <stdint.h>

// ---------------- problem constants ----------------
#define NODES 50000
#define F_IN 128
#define F_H1 256
#define F_H2 256
#define F_OUT 64

using f32x4   = __attribute__((ext_vector_type(4))) float;
using bf16x8  = __attribute__((ext_vector_type(8))) short;     // 8 bf16 in 4 VGPRs
using ushort4v = __attribute__((ext_vector_type(4))) unsigned short;
using ushort8v = __attribute__((ext_vector_type(8))) unsigned short;

// ---------------- bf16 split helpers ----------------
__device__ __forceinline__ unsigned short f2bf(float f) {
  union { float f; uint32_t u; } v; v.f = f;
  uint32_t r = v.u + 0x7FFFu + ((v.u >> 16) & 1u);   // round-to-nearest-even
  return (unsigned short)(r >> 16);
}
__device__ __forceinline__ float bf2f(unsigned short h) {
  union { uint32_t u; float f; } v; v.u = (uint32_t)h << 16;
  return v.f;
}

// ---------------- degree / CSR build ----------------
__global__ void k_init(int* deg_out, int* deg_in, int* cursor, int n) {
  int i = blockIdx.x * blockDim.x + threadIdx.x;
  if (i < n) { deg_out[i] = 1; deg_in[i] = 1; cursor[i] = 0; }  // self-loop counts as 1
}

__global__ void k_count(const int* __restrict__ src, const int* __restrict__ dst,
                        int* deg_out, int* deg_in, int e) {
  int i = blockIdx.x * blockDim.x + threadIdx.x;
  if (i < e) {
    atomicAdd(&deg_out[src[i]], 1);
    atomicAdd(&deg_in[dst[i]], 1);
  }
}

__global__ void k_norm(const int* __restrict__ deg_out, const int* __restrict__ deg_in,
                       float* ns, float* nd, int n) {
  int i = blockIdx.x * blockDim.x + threadIdx.x;
  if (i < n) {
    ns[i] = rsqrtf((float)deg_out[i]);
    nd[i] = rsqrtf((float)deg_in[i]);
  }
}

// exclusive prefix over (deg_in - 1): CSR row_ptr (self-loops NOT stored in CSR)
__global__ __launch_bounds__(1024) void k_scan(const int* __restrict__ deg_in,
                                               int* __restrict__ row_ptr, int n) {
  __shared__ int sums[1024];
  const int t = threadIdx.x;
  const int C = (n + 1023) / 1024;
  const int base = t * C;
  int s = 0;
  for (int i = 0; i < C; ++i) {
    int idx = base + i;
    if (idx < n) s += deg_in[idx] - 1;
  }
  sums[t] = s;
  __syncthreads();
  for (int off = 1; off < 1024; off <<= 1) {
    int v = (t >= off) ? sums[t - off] : 0;
    __syncthreads();
    sums[t] += v;
    __syncthreads();
  }
  int run = (t == 0) ? 0 : sums[t - 1];
  for (int i = 0; i < C; ++i) {
    int idx = base + i;
    if (idx < n) { row_ptr[idx] = run; run += deg_in[idx] - 1; }
  }
  if (t == 1023) row_ptr[n] = sums[1023];
}

__global__ void k_scatter(const int* __restrict__ src, const int* __restrict__ dst,
                          const int* __restrict__ row_ptr, int* cursor,
                          int* __restrict__ csr_src, int e) {
  int i = blockIdx.x * blockDim.x + threadIdx.x;
  if (i < e) {
    int d = dst[i];
    int pos = row_ptr[d] + atomicAdd(&cursor[d], 1);
    csr_src[pos] = src[i];
  }
}

// ---------------- feats prescale: Y = ns[row] * X (row-major [n][128]) ----------------
__global__ void k_prescale(const float* __restrict__ X, const float* __restrict__ ns,
                           float* __restrict__ Y, int total4, int ld4) {
  int i = blockIdx.x * blockDim.x + threadIdx.x;
  if (i < total4) {
    int row = i / ld4;
    float s = ns[row];
    float4 v = reinterpret_cast<const float4*>(X)[i];
    v.x *= s; v.y *= s; v.z *= s; v.w *= s;
    reinterpret_cast<float4*>(Y)[i] = v;
  }
}

// ---------------- weight prep: W[K][NOUT] f32 -> Wt_hi/Wt_lo [NOUT][K] bf16 ----
__global__ void k_wprep(const float* __restrict__ W, unsigned short* __restrict__ Wt_hi,
                        unsigned short* __restrict__ Wt_lo, int K, int NOUT) {
  int i = blockIdx.x * blockDim.x + threadIdx.x;
  if (i < K * NOUT) {
    int k = i / NOUT, n = i % NOUT;
    float w = W[i];
    unsigned short h = f2bf(w);
    unsigned short l = f2bf(w - bf2f(h));
    Wt_hi[(size_t)n * K + k] = h;
    Wt_lo[(size_t)n * K + k] = l;
  }
}

// ---------------- SpMM: Y[v] = nd[v] * ( X[v] + sum_{u->v} X[u] ) (+bias)
// X pre-scaled by ns upstream. float4 per lane; D/4 lanes per node; 64*4/D nodes/wave.
// 8-edge batches with next-batch index prefetch (hides idx latency under gathers).
template <int D, bool BIAS>
__global__ __launch_bounds__(256) void k_spmm(
    const float* __restrict__ X, const int* __restrict__ row_ptr,
    const int* __restrict__ csr_src, const float* __restrict__ nd,
    const float* __restrict__ bias, float* __restrict__ Y, int n) {
  constexpr int LPN = D / 4;        // lanes per node (float4 each)
  constexpr int NPW = 64 / LPN;     // nodes per wave
  const int wid = (blockIdx.x * blockDim.x + threadIdx.x) >> 6;
  const int lane = threadIdx.x & 63;
  const int g = lane / LPN;
  const int l = lane % LPN;
  const int v = wid * NPW + g;
  if (v >= n) return;
  const int off = l * 4;
  const float* __restrict__ Xo = X + off;

  float4 acc = *reinterpret_cast<const float4*>(X + (size_t)v * D + off);  // self term

  const int end = row_ptr[v + 1];
  int e = row_ptr[v];

  int u[8];
  if (e + 8 <= end) {
#pragma unroll
    for (int j = 0; j < 8; ++j) u[j] = csr_src[e + j];
  }
  while (e + 8 <= end) {
    int uc[8];
#pragma unroll
    for (int j = 0; j < 8; ++j) uc[j] = u[j];
    const int en = e + 8;
    if (en + 8 <= end) {
#pragma unroll
      for (int j = 0; j < 8; ++j) u[j] = csr_src[en + j];
    }
    float4 t[8];
#pragma unroll
    for (int j = 0; j < 8; ++j)
      t[j] = *reinterpret_cast<const float4*>(Xo + (size_t)uc[j] * D);
#pragma unroll
    for (int j = 0; j < 8; ++j) {
      acc.x += t[j].x; acc.y += t[j].y; acc.z += t[j].z; acc.w += t[j].w;
    }
    e = en;
  }
  if (e + 4 <= end) {
    float4 t0 = *reinterpret_cast<const float4*>(Xo + (size_t)csr_src[e + 0] * D);
    float4 t1 = *reinterpret_cast<const float4*>(Xo + (size_t)csr_src[e + 1] * D);
    float4 t2 = *reinterpret_cast<const float4*>(Xo + (size_t)csr_src[e + 2] * D);
    float4 t3 = *reinterpret_cast<const float4*>(Xo + (size_t)csr_src[e + 3] * D);
    acc.x += t0.x + t1.x + t2.x + t3.x;
    acc.y += t0.y + t1.y + t2.y + t3.y;
    acc.z += t0.z + t1.z + t2.z + t3.z;
    acc.w += t0.w + t1.w + t2.w + t3.w;
    e += 4;
  }
  for (; e < end; ++e) {
    float4 t = *reinterpret_cast<const float4*>(Xo + (size_t)csr_src[e] * D);
    acc.x += t.x; acc.y += t.y; acc.z += t.z; acc.w += t.w;
  }

  const float sc = nd[v];
  float4 o;
  o.x = sc * acc.x; o.y = sc * acc.y; o.z = sc * acc.z; o.w = sc * acc.w;
  if (BIAS) {
    float4 bb = *reinterpret_cast<const float4*>(bias + off);
    o.x += bb.x; o.y += bb.y; o.z += bb.z; o.w += bb.w;
  }
  *reinterpret_cast<float4*>(Y + (size_t)v * D + off) = o;
}

// ---------------- split-bf16 MFMA GEMM ----------------
// C[M][NOUT] = op( A[M][K] @ W[K][NOUT] (+bias) ) [* ns[row] if NSOUT]
// via A_hi*W_hi + A_hi*W_lo + A_lo*W_hi with mfma_f32_16x16x32_bf16.
// W pre-split & pre-transposed: Wt[n][k] bf16.
template <int K, int NOUT, int BM, int WM, int WN, int MF, int NF,
          bool RELU, bool BIAS, bool NSOUT>
__global__ __launch_bounds__(256) void k_gemm_mfma(
    const float* __restrict__ A,
    const unsigned short* __restrict__ Wt_hi, const unsigned short* __restrict__ Wt_lo,
    const float* __restrict__ bias, const float* __restrict__ ns,
    float* __restrict__ C, int M) {
  constexpr int BN = WN * NF * 16;
  static_assert(BM == WM * MF * 16, "BM mismatch");
  static_assert(BN == NOUT, "BN must equal NOUT");
  constexpr int LDP = 40;  // row pad: 80B stride -> bank stride 20 -> <=2-way (free), 16B aligned

  __shared__ unsigned short As[2][BM][LDP];   // [hi/lo][row][k]
  __shared__ unsigned short Ws[2][BN][LDP];   // [hi/lo][col][k]

  const int tid = threadIdx.x;
  const int bm = blockIdx.x * BM;
  const int lane = tid & 63;
  const int wave = tid >> 6;
  const int wmi = wave / WN;
  const int wni = wave % WN;
  const int rl = lane & 15;
  const int kg = lane >> 4;       // 0..3
  const int kb = kg * 8;

  f32x4 acc[MF][NF];
#pragma unroll
  for (int m = 0; m < MF; ++m)
#pragma unroll
    for (int n = 0; n < NF; ++n) acc[m][n] = (f32x4){0.f, 0.f, 0.f, 0.f};

  for (int kk = 0; kk < K; kk += 32) {
    // ---- stage A tile (BM x 32 f32), split into hi/lo bf16 ----
#pragma unroll
    for (int s0 = 0; s0 < BM * 8; s0 += 256) {
      int s = s0 + tid;
      int r = s >> 3, c4 = (s & 7) << 2;
      int grow = bm + r;
      float4 v = make_float4(0.f, 0.f, 0.f, 0.f);
      if (grow < M) {
        v = *reinterpret_cast<const float4*>(A + (size_t)grow * K + kk + c4);
      }
      ushort4v hi, lo;
      hi[0] = f2bf(v.x); lo[0] = f2bf(v.x - bf2f(hi[0]));
      hi[1] = f2bf(v.y); lo[1] = f2bf(v.y - bf2f(hi[1]));
      hi[2] = f2bf(v.z); lo[2] = f2bf(v.z - bf2f(hi[2]));
      hi[3] = f2bf(v.w); lo[3] = f2bf(v.w - bf2f(hi[3]));
      *reinterpret_cast<ushort4v*>(&As[0][r][c4]) = hi;
      *reinterpret_cast<ushort4v*>(&As[1][r][c4]) = lo;
    }
    // ---- stage W tile (BN cols x 32 k), already bf16, transposed in global ----
#pragma unroll
    for (int s0 = 0; s0 < BN * 4; s0 += 256) {
      int s = s0 + tid;
      int n = s >> 2, k8 = (s & 3) << 3;
      *reinterpret_cast<ushort8v*>(&Ws[0][n][k8]) =
          *reinterpret_cast<const ushort8v*>(Wt_hi + (size_t)n * K + kk + k8);
      *reinterpret_cast<ushort8v*>(&Ws[1][n][k8]) =
          *reinterpret_cast<const ushort8v*>(Wt_lo + (size_t)n * K + kk + k8);
    }
    __syncthreads();

    bf16x8 af[2][MF], bfr[2][NF];
#pragma unroll
    for (int m = 0; m < MF; ++m) {
      const int r = wmi * MF * 16 + m * 16 + rl;
      af[0][m] = *reinterpret_cast<const bf16x8*>(&As[0][r][kb]);
      af[1][m] = *reinterpret_cast<const bf16x8*>(&As[1][r][kb]);
    }
#pragma unroll
    for (int n = 0; n < NF; ++n) {
      const int c = wni * NF * 16 + n * 16 + rl;
      bfr[0][n] = *reinterpret_cast<const bf16x8*>(&Ws[0][c][kb]);
      bfr[1][n] = *reinterpret_cast<const bf16x8*>(&Ws[1][c][kb]);
    }
#pragma unroll
    for (int m = 0; m < MF; ++m)
#pragma unroll
      for (int n = 0; n < NF; ++n) {
        acc[m][n] = __builtin_amdgcn_mfma_f32_16x16x32_bf16(af[0][m], bfr[0][n], acc[m][n], 0, 0, 0);
        acc[m][n] = __builtin_amdgcn_mfma_f32_16x16x32_bf16(af[0][m], bfr[1][n], acc[m][n], 0, 0, 0);
        acc[m][n] = __builtin_amdgcn_mfma_f32_16x16x32_bf16(af[1][m], bfr[0][n], acc[m][n], 0, 0, 0);
      }
    __syncthreads();
  }

  // ---- epilogue ----
#pragma unroll
  for (int m = 0; m < MF; ++m) {
#pragma unroll
    for (int n = 0; n < NF; ++n) {
      const int col = wni * NF * 16 + n * 16 + rl;
      const float bb = BIAS ? bias[col] : 0.f;
      const int rowbase = bm + wmi * MF * 16 + m * 16 + kg * 4;
#pragma unroll
      for (int i = 0; i < 4; ++i) {
        int grow = rowbase + i;
        if (grow < M) {
          float val = acc[m][n][i] + bb;
          if (RELU) val = fmaxf(val, 0.f);
          if (NSOUT) val *= ns[grow];
          C[(size_t)grow * NOUT + col] = val;
        }
      }
    }
  }
}

// ---------------- launch ----------------
extern "C" void kernel_launch(void* const* d_in, const int* in_sizes, int n_in,
                              void* d_out, int out_size, void* d_ws, size_t ws_size,
                              hipStream_t stream) {
  const float* feats = (const float*)d_in[0];
  const float* W1 = (const float*)d_in[1];
  const float* b1 = (const float*)d_in[2];
  const float* W2 = (const float*)d_in[3];
  const float* b2 = (const float*)d_in[4];
  const float* W3 = (const float*)d_in[5];
  const float* b3 = (const float*)d_in[6];
  const int* src = (const int*)d_in[7];
  const int* dst = (const int*)d_in[8];
  float* out = (float*)d_out;
  const int N = NODES;
  const int E = in_sizes[7];

  char* ws = (char*)d_ws;
  size_t off = 0;
  auto alloc = [&](size_t bytes) -> void* {
    void* p = ws + off;
    off += (bytes + 255) & ~(size_t)255;
    return p;
  };
  float* bufA = (float*)alloc((size_t)N * 256 * sizeof(float));
  float* bufB = (float*)alloc((size_t)N * 256 * sizeof(float));
  int* deg_out = (int*)alloc((size_t)N * sizeof(int));
  int* deg_in = (int*)alloc((size_t)N * sizeof(int));
  int* cursor = (int*)alloc((size_t)N * sizeof(int));
  float* ns = (float*)alloc((size_t)N * sizeof(float));
  float* nd = (float*)alloc((size_t)N * sizeof(float));
  int* row_ptr = (int*)alloc((size_t)(N + 1) * sizeof(int));
  int* csr_src = (int*)alloc((size_t)E * sizeof(int));
  unsigned short* w1hi = (unsigned short*)alloc((size_t)F_IN * F_H1 * 2);
  unsigned short* w1lo = (unsigned short*)alloc((size_t)F_IN * F_H1 * 2);
  unsigned short* w2hi = (unsigned short*)alloc((size_t)F_H1 * F_H2 * 2);
  unsigned short* w2lo = (unsigned short*)alloc((size_t)F_H1 * F_H2 * 2);
  unsigned short* w3hi = (unsigned short*)alloc((size_t)F_H2 * F_OUT * 2);
  unsigned short* w3lo = (unsigned short*)alloc((size_t)F_H2 * F_OUT * 2);
  (void)ws_size; (void)n_in; (void)out_size;

  // ---- weight split/transpose (tiny) ----
  hipLaunchKernelGGL(k_wprep, dim3((F_IN * F_H1 + 255) / 256), dim3(256), 0, stream,
                     W1, w1hi, w1lo, F_IN, F_H1);
  hipLaunchKernelGGL(k_wprep, dim3((F_H1 * F_H2 + 255) / 256), dim3(256), 0, stream,
                     W2, w2hi, w2lo, F_H1, F_H2);
  hipLaunchKernelGGL(k_wprep, dim3((F_H2 * F_OUT + 255) / 256), dim3(256), 0, stream,
                     W3, w3hi, w3lo, F_H2, F_OUT);

  // ---- graph preprocessing (every call; deterministic work) ----
  hipLaunchKernelGGL(k_init, dim3((N + 255) / 256), dim3(256), 0, stream,
                     deg_out, deg_in, cursor, N);
  hipLaunchKernelGGL(k_count, dim3((E + 255) / 256), dim3(256), 0, stream,
                     src, dst, deg_out, deg_in, E);
  hipLaunchKernelGGL(k_norm, dim3((N + 255) / 256), dim3(256), 0, stream,
                     deg_out, deg_in, ns, nd, N);
  hipLaunchKernelGGL(k_scan, dim3(1), dim3(1024), 0, stream, deg_in, row_ptr, N);
  hipLaunchKernelGGL(k_scatter, dim3((E + 255) / 256), dim3(256), 0, stream,
                     src, dst, row_ptr, cursor, csr_src, E);

  // ---- prescale feats by ns (removes per-edge ns gather in spmm1) ----
  hipLaunchKernelGGL(k_prescale, dim3((N * 32 + 255) / 256), dim3(256), 0, stream,
                     feats, ns, bufA, N * 32, 32);

  auto spmm_grid = [](int waves) { return dim3((waves * 64 + 255) / 256); };

  // ---- layer 1: SpMM(d=128, 2 nodes/wave) then MFMA-GEMM 128->256 (+b1, relu, *ns) ----
  hipLaunchKernelGGL((k_spmm<128, false>), spmm_grid((N + 1) / 2), dim3(256), 0, stream,
                     bufA, row_ptr, csr_src, nd, nullptr, bufB, N);
  hipLaunchKernelGGL((k_gemm_mfma<128, 256, 64, 1, 4, 4, 4, true, true, true>),
                     dim3((N + 63) / 64), dim3(256), 0, stream,
                     bufB, w1hi, w1lo, b1, ns, bufA, N);

  // ---- layer 2: SpMM(d=256, 1 node/wave) then MFMA-GEMM 256->256 (+b2, relu, *ns) ----
  hipLaunchKernelGGL((k_spmm<256, false>), spmm_grid(N), dim3(256), 0, stream,
                     bufA, row_ptr, csr_src, nd, nullptr, bufB, N);
  hipLaunchKernelGGL((k_gemm_mfma<256, 256, 64, 1, 4, 4, 4, true, true, true>),
                     dim3((N + 63) / 64), dim3(256), 0, stream,
                     bufB, w2hi, w2lo, b2, ns, bufA, N);

  // ---- layer 3: plain MFMA-GEMM 256->64 (input already ns-scaled), then SpMM(d=64, 4 nodes/wave) +b3 ----
  hipLaunchKernelGGL((k_gemm_mfma<256, 64, 128, 4, 1, 2, 4, false, false, false>),
                     dim3((N + 127) / 128), dim3(256), 0, stream,
                     bufA, w3hi, w3lo, nullptr, nullptr, bufB, N);
  hipLaunchKernelGGL((k_spmm<64, true>), spmm_grid((N + 3) / 4), dim3(256), 0, stream,
                     bufB, row_ptr, csr_src, nd, b3, out, N);
}

// Round 4
// 503.709 us; speedup vs baseline: 1.0772x; 1.0772x over previous
//
#include <hip/hip_runtime.h>
#include <hip/hip_fp16.h>
#include <stdint.h>

// ---------------- problem constants ----------------
#define NODES 50000
#define F_IN 128
#define F_H1 256
#define F_H2 256
#define F_OUT 64

using f32x4   = __attribute__((ext_vector_type(4))) float;
using bf16x8  = __attribute__((ext_vector_type(8))) short;     // 8 bf16 in 4 VGPRs
using ushort4v = __attribute__((ext_vector_type(4))) unsigned short;
using ushort8v = __attribute__((ext_vector_type(8))) unsigned short;

// ---------------- bf16 split helpers ----------------
__device__ __forceinline__ unsigned short f2bf(float f) {
  union { float f; uint32_t u; } v; v.f = f;
  uint32_t r = v.u + 0x7FFFu + ((v.u >> 16) & 1u);   // round-to-nearest-even
  return (unsigned short)(r >> 16);
}
__device__ __forceinline__ float bf2f(unsigned short h) {
  union { uint32_t u; float f; } v; v.u = (uint32_t)h << 16;
  return v.f;
}

// ---------------- degree / CSR build ----------------
__global__ void k_init(int* deg_out, int* deg_in, int* cursor, int n) {
  int i = blockIdx.x * blockDim.x + threadIdx.x;
  if (i < n) { deg_out[i] = 1; deg_in[i] = 1; cursor[i] = 0; }  // self-loop counts as 1
}

__global__ void k_count(const int* __restrict__ src, const int* __restrict__ dst,
                        int* deg_out, int* deg_in, int e) {
  int i = blockIdx.x * blockDim.x + threadIdx.x;
  if (i < e) {
    atomicAdd(&deg_out[src[i]], 1);
    atomicAdd(&deg_in[dst[i]], 1);
  }
}

__global__ void k_norm(const int* __restrict__ deg_out, const int* __restrict__ deg_in,
                       float* ns, float* nd, int n) {
  int i = blockIdx.x * blockDim.x + threadIdx.x;
  if (i < n) {
    ns[i] = rsqrtf((float)deg_out[i]);
    nd[i] = rsqrtf((float)deg_in[i]);
  }
}

// exclusive prefix over (deg_in - 1): CSR row_ptr (self-loops NOT stored in CSR)
__global__ __launch_bounds__(1024) void k_scan(const int* __restrict__ deg_in,
                                               int* __restrict__ row_ptr, int n) {
  __shared__ int sums[1024];
  const int t = threadIdx.x;
  const int C = (n + 1023) / 1024;
  const int base = t * C;
  int s = 0;
  for (int i = 0; i < C; ++i) {
    int idx = base + i;
    if (idx < n) s += deg_in[idx] - 1;
  }
  sums[t] = s;
  __syncthreads();
  for (int off = 1; off < 1024; off <<= 1) {
    int v = (t >= off) ? sums[t - off] : 0;
    __syncthreads();
    sums[t] += v;
    __syncthreads();
  }
  int run = (t == 0) ? 0 : sums[t - 1];
  for (int i = 0; i < C; ++i) {
    int idx = base + i;
    if (idx < n) { row_ptr[idx] = run; run += deg_in[idx] - 1; }
  }
  if (t == 1023) row_ptr[n] = sums[1023];
}

__global__ void k_scatter(const int* __restrict__ src, const int* __restrict__ dst,
                          const int* __restrict__ row_ptr, int* cursor,
                          int* __restrict__ csr_src, int e) {
  int i = blockIdx.x * blockDim.x + threadIdx.x;
  if (i < e) {
    int d = dst[i];
    int pos = row_ptr[d] + atomicAdd(&cursor[d], 1);
    csr_src[pos] = src[i];
  }
}

// ---------------- feats prescale -> fp16: Y = fp16(ns[row] * X), X:[n][128] ----------------
__global__ void k_prescale_h(const float* __restrict__ X, const float* __restrict__ ns,
                             __half* __restrict__ Y, int total4) {
  int i = blockIdx.x * blockDim.x + threadIdx.x;
  if (i < total4) {
    int row = i >> 5;                       // 32 float4 per 128-col row
    float s = ns[row];
    float4 v = reinterpret_cast<const float4*>(X)[i];
    __half2 h0 = __floats2half2_rn(v.x * s, v.y * s);
    __half2 h1 = __floats2half2_rn(v.z * s, v.w * s);
    union { struct { __half2 a, b; } h; uint2 u; } o;
    o.h.a = h0; o.h.b = h1;
    reinterpret_cast<uint2*>(Y)[i] = o.u;
  }
}

// ---------------- weight prep: W[K][NOUT] f32 -> Wt_hi/Wt_lo [NOUT][K] bf16 ----
__global__ void k_wprep(const float* __restrict__ W, unsigned short* __restrict__ Wt_hi,
                        unsigned short* __restrict__ Wt_lo, int K, int NOUT) {
  int i = blockIdx.x * blockDim.x + threadIdx.x;
  if (i < K * NOUT) {
    int k = i / NOUT, n = i % NOUT;
    float w = W[i];
    unsigned short h = f2bf(w);
    unsigned short l = f2bf(w - bf2f(h));
    Wt_hi[(size_t)n * K + k] = h;
    Wt_lo[(size_t)n * K + k] = l;
  }
}

// ---------------- fp16 gather helpers ----------------
template <int HPL> struct raw_t_sel;
template <> struct raw_t_sel<1> { using type = unsigned short; };
template <> struct raw_t_sel<2> { using type = unsigned int; };
template <> struct raw_t_sel<4> { using type = uint2; };

template <int HPL>
__device__ __forceinline__ typename raw_t_sel<HPL>::type graw(const __half* p) {
  return *reinterpret_cast<const typename raw_t_sel<HPL>::type*>(p);
}
template <int HPL>
__device__ __forceinline__ void raw_acc(float* acc, typename raw_t_sel<HPL>::type r) {
  if constexpr (HPL == 4) {
    union { unsigned u; __half2 h; } a, b;
    a.u = r.x; b.u = r.y;
    float2 f0 = __half22float2(a.h), f1 = __half22float2(b.h);
    acc[0] += f0.x; acc[1] += f0.y; acc[2] += f1.x; acc[3] += f1.y;
  } else if constexpr (HPL == 2) {
    union { unsigned u; __half2 h; } a; a.u = r;
    float2 f0 = __half22float2(a.h);
    acc[0] += f0.x; acc[1] += f0.y;
  } else {
    union { unsigned short u; __half h; } a; a.u = r;
    acc[0] += __half2float(a.h);
  }
}

// ---------------- SpMM (fp16 source): Y[v] = nd[v]*(X[v] + sum_{u->v} X[u]) (+bias), f32 out
// WPN waves per node (disjoint feature halves); HPL halves per lane.
template <int D, int WPN, bool BIAS>
__global__ __launch_bounds__(256) void k_spmm_h(
    const __half* __restrict__ X, const int* __restrict__ row_ptr,
    const int* __restrict__ csr_src, const float* __restrict__ nd,
    const float* __restrict__ bias, float* __restrict__ Y, int n) {
  constexpr int HPL = D / (64 * WPN);
  static_assert(HPL >= 1 && HPL <= 4, "bad HPL");
  using raw_t = typename raw_t_sel<HPL>::type;
  const int gw = (blockIdx.x * blockDim.x + threadIdx.x) >> 6;
  const int lane = threadIdx.x & 63;
  const int v = (WPN == 2) ? (gw >> 1) : gw;
  const int part = (WPN == 2) ? (gw & 1) : 0;
  if (v >= n) return;
  const int off = part * 64 * HPL + lane * HPL;
  const __half* __restrict__ Xo = X + off;

  float acc[HPL] = {};
  raw_acc<HPL>(acc, graw<HPL>(Xo + (size_t)v * D));   // self term

  const int end = row_ptr[v + 1];
  int e = row_ptr[v];
  for (; e + 4 <= end; e += 4) {
    int u0 = csr_src[e + 0], u1 = csr_src[e + 1];
    int u2 = csr_src[e + 2], u3 = csr_src[e + 3];
    raw_t r0 = graw<HPL>(Xo + (size_t)u0 * D);
    raw_t r1 = graw<HPL>(Xo + (size_t)u1 * D);
    raw_t r2 = graw<HPL>(Xo + (size_t)u2 * D);
    raw_t r3 = graw<HPL>(Xo + (size_t)u3 * D);
    raw_acc<HPL>(acc, r0); raw_acc<HPL>(acc, r1);
    raw_acc<HPL>(acc, r2); raw_acc<HPL>(acc, r3);
  }
  for (; e < end; ++e) {
    raw_acc<HPL>(acc, graw<HPL>(Xo + (size_t)csr_src[e] * D));
  }

  const float sc = nd[v];
  float o[HPL];
#pragma unroll
  for (int i = 0; i < HPL; ++i) {
    o[i] = sc * acc[i];
    if (BIAS) o[i] += bias[off + i];
  }
  float* yp = Y + (size_t)v * D + off;
  if constexpr (HPL == 4) *reinterpret_cast<float4*>(yp) = make_float4(o[0], o[1], o[2], o[3]);
  else if constexpr (HPL == 2) *reinterpret_cast<float2*>(yp) = make_float2(o[0], o[1]);
  else *yp = o[0];
}

// ---------------- split-bf16 MFMA GEMM ----------------
// C[M][NOUT] = op( A[M][K] @ W[K][NOUT] (+bias) ) [* ns[row] if NSOUT]
// via A_hi*W_hi + A_hi*W_lo + A_lo*W_hi with mfma_f32_16x16x32_bf16.
// AHALF: A is fp16 (exact into hi+lo).  OHALF: C written as fp16.
template <int K, int NOUT, int BM, int WM, int WN, int MF, int NF,
          bool RELU, bool BIAS, bool NSOUT, bool AHALF, bool OHALF>
__global__ __launch_bounds__(256) void k_gemm_mfma(
    const void* __restrict__ A,
    const unsigned short* __restrict__ Wt_hi, const unsigned short* __restrict__ Wt_lo,
    const float* __restrict__ bias, const float* __restrict__ ns,
    void* __restrict__ C, int M) {
  constexpr int BN = WN * NF * 16;
  static_assert(BM == WM * MF * 16, "BM mismatch");
  static_assert(BN == NOUT, "BN must equal NOUT");
  constexpr int LDP = 40;  // 80B row stride -> bank stride 20 -> <=2-way (free), 16B aligned

  __shared__ unsigned short As[2][BM][LDP];   // [hi/lo][row][k]
  __shared__ unsigned short Ws[2][BN][LDP];   // [hi/lo][col][k]

  const int tid = threadIdx.x;
  const int bm = blockIdx.x * BM;
  const int lane = tid & 63;
  const int wave = tid >> 6;
  const int wmi = wave / WN;
  const int wni = wave % WN;
  const int rl = lane & 15;
  const int kg = lane >> 4;       // 0..3
  const int kb = kg * 8;

  f32x4 acc[MF][NF];
#pragma unroll
  for (int m = 0; m < MF; ++m)
#pragma unroll
    for (int n = 0; n < NF; ++n) acc[m][n] = (f32x4){0.f, 0.f, 0.f, 0.f};

  for (int kk = 0; kk < K; kk += 32) {
    // ---- stage A tile (BM x 32), split into hi/lo bf16 ----
#pragma unroll
    for (int s0 = 0; s0 < BM * 8; s0 += 256) {
      int s = s0 + tid;
      int r = s >> 3, c4 = (s & 7) << 2;
      int grow = bm + r;
      float4 v = make_float4(0.f, 0.f, 0.f, 0.f);
      if (grow < M) {
        if constexpr (AHALF) {
          const __half* Ah = reinterpret_cast<const __half*>(A);
          uint2 raw = *reinterpret_cast<const uint2*>(Ah + (size_t)grow * K + kk + c4);
          union { unsigned u; __half2 h; } a, b;
          a.u = raw.x; b.u = raw.y;
          float2 f0 = __half22float2(a.h), f1 = __half22float2(b.h);
          v = make_float4(f0.x, f0.y, f1.x, f1.y);
        } else {
          v = *reinterpret_cast<const float4*>(
              reinterpret_cast<const float*>(A) + (size_t)grow * K + kk + c4);
        }
      }
      ushort4v hi, lo;
      hi[0] = f2bf(v.x); lo[0] = f2bf(v.x - bf2f(hi[0]));
      hi[1] = f2bf(v.y); lo[1] = f2bf(v.y - bf2f(hi[1]));
      hi[2] = f2bf(v.z); lo[2] = f2bf(v.z - bf2f(hi[2]));
      hi[3] = f2bf(v.w); lo[3] = f2bf(v.w - bf2f(hi[3]));
      *reinterpret_cast<ushort4v*>(&As[0][r][c4]) = hi;
      *reinterpret_cast<ushort4v*>(&As[1][r][c4]) = lo;
    }
    // ---- stage W tile (BN cols x 32 k), bf16, pre-transposed ----
#pragma unroll
    for (int s0 = 0; s0 < BN * 4; s0 += 256) {
      int s = s0 + tid;
      int n = s >> 2, k8 = (s & 3) << 3;
      *reinterpret_cast<ushort8v*>(&Ws[0][n][k8]) =
          *reinterpret_cast<const ushort8v*>(Wt_hi + (size_t)n * K + kk + k8);
      *reinterpret_cast<ushort8v*>(&Ws[1][n][k8]) =
          *reinterpret_cast<const ushort8v*>(Wt_lo + (size_t)n * K + kk + k8);
    }
    __syncthreads();

    bf16x8 af[2][MF], bfr[2][NF];
#pragma unroll
    for (int m = 0; m < MF; ++m) {
      const int r = wmi * MF * 16 + m * 16 + rl;
      af[0][m] = *reinterpret_cast<const bf16x8*>(&As[0][r][kb]);
      af[1][m] = *reinterpret_cast<const bf16x8*>(&As[1][r][kb]);
    }
#pragma unroll
    for (int n = 0; n < NF; ++n) {
      const int c = wni * NF * 16 + n * 16 + rl;
      bfr[0][n] = *reinterpret_cast<const bf16x8*>(&Ws[0][c][kb]);
      bfr[1][n] = *reinterpret_cast<const bf16x8*>(&Ws[1][c][kb]);
    }
#pragma unroll
    for (int m = 0; m < MF; ++m)
#pragma unroll
      for (int n = 0; n < NF; ++n) {
        acc[m][n] = __builtin_amdgcn_mfma_f32_16x16x32_bf16(af[0][m], bfr[0][n], acc[m][n], 0, 0, 0);
        acc[m][n] = __builtin_amdgcn_mfma_f32_16x16x32_bf16(af[0][m], bfr[1][n], acc[m][n], 0, 0, 0);
        acc[m][n] = __builtin_amdgcn_mfma_f32_16x16x32_bf16(af[1][m], bfr[0][n], acc[m][n], 0, 0, 0);
      }
    __syncthreads();
  }

  // ---- epilogue ----
#pragma unroll
  for (int m = 0; m < MF; ++m) {
#pragma unroll
    for (int n = 0; n < NF; ++n) {
      const int col = wni * NF * 16 + n * 16 + rl;
      const float bb = BIAS ? bias[col] : 0.f;
      const int rowbase = bm + wmi * MF * 16 + m * 16 + kg * 4;
#pragma unroll
      for (int i = 0; i < 4; ++i) {
        int grow = rowbase + i;
        if (grow < M) {
          float val = acc[m][n][i] + bb;
          if (RELU) val = fmaxf(val, 0.f);
          if (NSOUT) val *= ns[grow];
          if constexpr (OHALF)
            reinterpret_cast<__half*>(C)[(size_t)grow * NOUT + col] = __float2half_rn(val);
          else
            reinterpret_cast<float*>(C)[(size_t)grow * NOUT + col] = val;
        }
      }
    }
  }
}

// ---------------- launch ----------------
extern "C" void kernel_launch(void* const* d_in, const int* in_sizes, int n_in,
                              void* d_out, int out_size, void* d_ws, size_t ws_size,
                              hipStream_t stream) {
  const float* feats = (const float*)d_in[0];
  const float* W1 = (const float*)d_in[1];
  const float* b1 = (const float*)d_in[2];
  const float* W2 = (const float*)d_in[3];
  const float* b2 = (const float*)d_in[4];
  const float* W3 = (const float*)d_in[5];
  const float* b3 = (const float*)d_in[6];
  const int* src = (const int*)d_in[7];
  const int* dst = (const int*)d_in[8];
  float* out = (float*)d_out;
  const int N = NODES;
  const int E = in_sizes[7];

  char* ws = (char*)d_ws;
  size_t off = 0;
  auto alloc = [&](size_t bytes) -> void* {
    void* p = ws + off;
    off += (bytes + 255) & ~(size_t)255;
    return p;
  };
  // W0: f32 N*256 (spmm2 out)
  // W1r: N*256 f32-capacity, used as f32 N*128 (spmm1 out) then fp16 N*256 (gemm2 out)
  // W2r: fp16 N*256 capacity: prescaled feats (N*128) -> gemm1 out (N*256) -> gemm3 out (N*64)
  float* w0 = (float*)alloc((size_t)N * 256 * sizeof(float));
  void* w1r = alloc((size_t)N * 256 * sizeof(__half) > (size_t)N * 128 * sizeof(float)
                        ? (size_t)N * 256 * sizeof(__half)
                        : (size_t)N * 128 * sizeof(float));
  __half* w2r = (__half*)alloc((size_t)N * 256 * sizeof(__half));
  int* deg_out = (int*)alloc((size_t)N * sizeof(int));
  int* deg_in = (int*)alloc((size_t)N * sizeof(int));
  int* cursor = (int*)alloc((size_t)N * sizeof(int));
  float* ns = (float*)alloc((size_t)N * sizeof(float));
  float* nd = (float*)alloc((size_t)N * sizeof(float));
  int* row_ptr = (int*)alloc((size_t)(N + 1) * sizeof(int));
  int* csr_src = (int*)alloc((size_t)E * sizeof(int));
  unsigned short* w1hi = (unsigned short*)alloc((size_t)F_IN * F_H1 * 2);
  unsigned short* w1lo = (unsigned short*)alloc((size_t)F_IN * F_H1 * 2);
  unsigned short* w2hi = (unsigned short*)alloc((size_t)F_H1 * F_H2 * 2);
  unsigned short* w2lo = (unsigned short*)alloc((size_t)F_H1 * F_H2 * 2);
  unsigned short* w3hi = (unsigned short*)alloc((size_t)F_H2 * F_OUT * 2);
  unsigned short* w3lo = (unsigned short*)alloc((size_t)F_H2 * F_OUT * 2);
  (void)ws_size; (void)n_in; (void)out_size;

  // ---- weight split/transpose (tiny) ----
  hipLaunchKernelGGL(k_wprep, dim3((F_IN * F_H1 + 255) / 256), dim3(256), 0, stream,
                     W1, w1hi, w1lo, F_IN, F_H1);
  hipLaunchKernelGGL(k_wprep, dim3((F_H1 * F_H2 + 255) / 256), dim3(256), 0, stream,
                     W2, w2hi, w2lo, F_H1, F_H2);
  hipLaunchKernelGGL(k_wprep, dim3((F_H2 * F_OUT + 255) / 256), dim3(256), 0, stream,
                     W3, w3hi, w3lo, F_H2, F_OUT);

  // ---- graph preprocessing ----
  hipLaunchKernelGGL(k_init, dim3((N + 255) / 256), dim3(256), 0, stream,
                     deg_out, deg_in, cursor, N);
  hipLaunchKernelGGL(k_count, dim3((E + 255) / 256), dim3(256), 0, stream,
                     src, dst, deg_out, deg_in, E);
  hipLaunchKernelGGL(k_norm, dim3((N + 255) / 256), dim3(256), 0, stream,
                     deg_out, deg_in, ns, nd, N);
  hipLaunchKernelGGL(k_scan, dim3(1), dim3(1024), 0, stream, deg_in, row_ptr, N);
  hipLaunchKernelGGL(k_scatter, dim3((E + 255) / 256), dim3(256), 0, stream,
                     src, dst, row_ptr, cursor, csr_src, E);

  // ---- prescale feats by ns -> fp16 ----
  hipLaunchKernelGGL(k_prescale_h, dim3((N * 32 + 255) / 256), dim3(256), 0, stream,
                     feats, ns, w2r, N * 32);

  auto grid_w = [](int waves) { return dim3((waves + 3) / 4); };  // 4 waves/block

  // ---- layer 1: SpMM(d=128, 2 waves/node, fp16) -> f32; GEMM 128->256 (+b1, relu, *ns) -> fp16
  hipLaunchKernelGGL((k_spmm_h<128, 2, false>), grid_w(N * 2), dim3(256), 0, stream,
                     w2r, row_ptr, csr_src, nd, nullptr, (float*)w1r, N);
  hipLaunchKernelGGL((k_gemm_mfma<128, 256, 64, 1, 4, 4, 4, true, true, true, false, true>),
                     dim3((N + 63) / 64), dim3(256), 0, stream,
                     w1r, w1hi, w1lo, b1, ns, w2r, N);

  // ---- layer 2: SpMM(d=256, 2 waves/node, fp16) -> f32; GEMM 256->256 (+b2, relu, *ns) -> fp16
  hipLaunchKernelGGL((k_spmm_h<256, 2, false>), grid_w(N * 2), dim3(256), 0, stream,
                     w2r, row_ptr, csr_src, nd, nullptr, w0, N);
  hipLaunchKernelGGL((k_gemm_mfma<256, 256, 64, 1, 4, 4, 4, true, true, true, false, true>),
                     dim3((N + 63) / 64), dim3(256), 0, stream,
                     w0, w2hi, w2lo, b2, ns, w1r, N);

  // ---- layer 3: GEMM 256->64 (fp16 A, no act) -> fp16; SpMM(d=64, fp16) +b3 -> out f32
  hipLaunchKernelGGL((k_gemm_mfma<256, 64, 128, 4, 1, 2, 4, false, false, false, true, true>),
                     dim3((N + 127) / 128), dim3(256), 0, stream,
                     w1r, w3hi, w3lo, nullptr, nullptr, w2r, N);
  hipLaunchKernelGGL((k_spmm_h<64, 1, true>), grid_w(N), dim3(256), 0, stream,
                     w2r, row_ptr, csr_src, nd, b3, out, N);
}

// Round 5
// 415.162 us; speedup vs baseline: 1.3069x; 1.2133x over previous
//
#include <hip/hip_runtime.h>
#include <hip/hip_fp16.h>
#include <stdint.h>

// ---------------- problem constants ----------------
#define NODES 50000
#define F_IN 128
#define F_H1 256
#define F_H2 256
#define F_OUT 64

using f32x4   = __attribute__((ext_vector_type(4))) float;
using bf16x8  = __attribute__((ext_vector_type(8))) short;     // 8 bf16 in 4 VGPRs
using ushort4v = __attribute__((ext_vector_type(4))) unsigned short;
using ushort8v = __attribute__((ext_vector_type(8))) unsigned short;

// ---------------- bf16 split helpers ----------------
__device__ __forceinline__ unsigned short f2bf(float f) {
  union { float f; uint32_t u; } v; v.f = f;
  uint32_t r = v.u + 0x7FFFu + ((v.u >> 16) & 1u);   // round-to-nearest-even
  return (unsigned short)(r >> 16);
}
__device__ __forceinline__ float bf2f(unsigned short h) {
  union { uint32_t u; float f; } v; v.u = (uint32_t)h << 16;
  return v.f;
}

// ---------------- degree / CSR build ----------------
__global__ void k_init(int* deg_out, int* deg_in, int* cursor, int n) {
  int i = blockIdx.x * blockDim.x + threadIdx.x;
  if (i < n) { deg_out[i] = 1; deg_in[i] = 1; cursor[i] = 0; }  // self-loop counts as 1
}

__global__ void k_count(const int* __restrict__ src, const int* __restrict__ dst,
                        int* deg_out, int* deg_in, int e) {
  int i = blockIdx.x * blockDim.x + threadIdx.x;
  if (i < e) {
    atomicAdd(&deg_out[src[i]], 1);
    atomicAdd(&deg_in[dst[i]], 1);
  }
}

__global__ void k_norm(const int* __restrict__ deg_out, const int* __restrict__ deg_in,
                       float* ns, float* nd, int n) {
  int i = blockIdx.x * blockDim.x + threadIdx.x;
  if (i < n) {
    ns[i] = rsqrtf((float)deg_out[i]);
    nd[i] = rsqrtf((float)deg_in[i]);
  }
}

// ---------------- parallel 3-phase exclusive scan over (deg_in - 1) ----------------
// phase 1: per-block (256 elems) sums
__global__ __launch_bounds__(256) void k_scan1(const int* __restrict__ deg_in,
                                               int* __restrict__ psum, int n) {
  int i = blockIdx.x * 256 + threadIdx.x;
  int v = (i < n) ? deg_in[i] - 1 : 0;
#pragma unroll
  for (int o = 1; o < 64; o <<= 1) v += __shfl_xor(v, o);
  __shared__ int ws[4];
  if ((threadIdx.x & 63) == 0) ws[threadIdx.x >> 6] = v;
  __syncthreads();
  if (threadIdx.x == 0) psum[blockIdx.x] = ws[0] + ws[1] + ws[2] + ws[3];
}

// phase 2: single small block exclusive-scans the partials (nb <= 256)
__global__ __launch_bounds__(256) void k_scan2(int* __restrict__ psum, int nb) {
  __shared__ int s[256];
  int t = threadIdx.x;
  int v = (t < nb) ? psum[t] : 0;
  s[t] = v;
  __syncthreads();
  for (int o = 1; o < 256; o <<= 1) {
    int u = (t >= o) ? s[t - o] : 0;
    __syncthreads();
    s[t] += u;
    __syncthreads();
  }
  if (t < nb) psum[t] = s[t] - v;   // exclusive
}

// phase 3: in-block scan + block offset -> row_ptr (exclusive); last elem writes row_ptr[n]
__global__ __launch_bounds__(256) void k_scan3(const int* __restrict__ deg_in,
                                               const int* __restrict__ psum,
                                               int* __restrict__ row_ptr, int n) {
  int i = blockIdx.x * 256 + threadIdx.x;
  int lane = threadIdx.x & 63;
  int w = threadIdx.x >> 6;
  int v = (i < n) ? deg_in[i] - 1 : 0;
  int x = v;
#pragma unroll
  for (int o = 1; o < 64; o <<= 1) {
    int u = __shfl_up(x, o);
    if (lane >= o) x += u;
  }
  __shared__ int wsum[4];
  if (lane == 63) wsum[w] = x;
  __syncthreads();
  int woff = 0;
#pragma unroll
  for (int j = 0; j < 4; ++j)
    if (j < w) woff += wsum[j];
  int excl = x - v + woff + psum[blockIdx.x];
  if (i < n) row_ptr[i] = excl;
  if (i == n - 1) row_ptr[n] = excl + v;
}

__global__ void k_scatter(const int* __restrict__ src, const int* __restrict__ dst,
                          const int* __restrict__ row_ptr, int* cursor,
                          int* __restrict__ csr_src, int e) {
  int i = blockIdx.x * blockDim.x + threadIdx.x;
  if (i < e) {
    int d = dst[i];
    int pos = row_ptr[d] + atomicAdd(&cursor[d], 1);
    csr_src[pos] = src[i];
  }
}

// ---------------- feats prescale -> fp16: Y = fp16(ns[row] * X), X:[n][128] ----------------
__global__ void k_prescale_h(const float* __restrict__ X, const float* __restrict__ ns,
                             __half* __restrict__ Y, int total4) {
  int i = blockIdx.x * blockDim.x + threadIdx.x;
  if (i < total4) {
    int row = i >> 5;                       // 32 float4 per 128-col row
    float s = ns[row];
    float4 v = reinterpret_cast<const float4*>(X)[i];
    __half2 h0 = __floats2half2_rn(v.x * s, v.y * s);
    __half2 h1 = __floats2half2_rn(v.z * s, v.w * s);
    union { struct { __half2 a, b; } h; uint2 u; } o;
    o.h.a = h0; o.h.b = h1;
    reinterpret_cast<uint2*>(Y)[i] = o.u;
  }
}

// ---------------- weight prep: W[K][NOUT] f32 -> Wt_hi/Wt_lo [NOUT][K] bf16 ----
__global__ void k_wprep(const float* __restrict__ W, unsigned short* __restrict__ Wt_hi,
                        unsigned short* __restrict__ Wt_lo, int K, int NOUT) {
  int i = blockIdx.x * blockDim.x + threadIdx.x;
  if (i < K * NOUT) {
    int k = i / NOUT, n = i % NOUT;
    float w = W[i];
    unsigned short h = f2bf(w);
    unsigned short l = f2bf(w - bf2f(h));
    Wt_hi[(size_t)n * K + k] = h;
    Wt_lo[(size_t)n * K + k] = l;
  }
}

// ---------------- fp16 gather helpers ----------------
template <int HPL> struct raw_t_sel;
template <> struct raw_t_sel<1> { using type = unsigned short; };
template <> struct raw_t_sel<2> { using type = unsigned int; };
template <> struct raw_t_sel<4> { using type = uint2; };

template <int HPL>
__device__ __forceinline__ typename raw_t_sel<HPL>::type graw(const __half* p) {
  return *reinterpret_cast<const typename raw_t_sel<HPL>::type*>(p);
}
template <int HPL>
__device__ __forceinline__ void raw_acc(float* acc, typename raw_t_sel<HPL>::type r) {
  if constexpr (HPL == 4) {
    union { unsigned u; __half2 h; } a, b;
    a.u = r.x; b.u = r.y;
    float2 f0 = __half22float2(a.h), f1 = __half22float2(b.h);
    acc[0] += f0.x; acc[1] += f0.y; acc[2] += f1.x; acc[3] += f1.y;
  } else if constexpr (HPL == 2) {
    union { unsigned u; __half2 h; } a; a.u = r;
    float2 f0 = __half22float2(a.h);
    acc[0] += f0.x; acc[1] += f0.y;
  } else {
    union { unsigned short u; __half h; } a; a.u = r;
    acc[0] += __half2float(a.h);
  }
}

// ---------------- SpMM (fp16 source): Y[v] = nd[v]*(X[v] + sum_{u->v} X[u]) (+bias), f32 out
// WPN waves per node (disjoint feature halves); HPL halves per lane.
template <int D, int WPN, bool BIAS>
__global__ __launch_bounds__(256) void k_spmm_h(
    const __half* __restrict__ X, const int* __restrict__ row_ptr,
    const int* __restrict__ csr_src, const float* __restrict__ nd,
    const float* __restrict__ bias, float* __restrict__ Y, int n) {
  constexpr int HPL = D / (64 * WPN);
  static_assert(HPL >= 1 && HPL <= 4, "bad HPL");
  using raw_t = typename raw_t_sel<HPL>::type;
  const int gw = (blockIdx.x * blockDim.x + threadIdx.x) >> 6;
  const int lane = threadIdx.x & 63;
  const int v = (WPN == 2) ? (gw >> 1) : gw;
  const int part = (WPN == 2) ? (gw & 1) : 0;
  if (v >= n) return;
  const int off = part * 64 * HPL + lane * HPL;
  const __half* __restrict__ Xo = X + off;

  float acc[HPL] = {};
  raw_acc<HPL>(acc, graw<HPL>(Xo + (size_t)v * D));   // self term

  const int end = row_ptr[v + 1];
  int e = row_ptr[v];
  for (; e + 4 <= end; e += 4) {
    int u0 = csr_src[e + 0], u1 = csr_src[e + 1];
    int u2 = csr_src[e + 2], u3 = csr_src[e + 3];
    raw_t r0 = graw<HPL>(Xo + (size_t)u0 * D);
    raw_t r1 = graw<HPL>(Xo + (size_t)u1 * D);
    raw_t r2 = graw<HPL>(Xo + (size_t)u2 * D);
    raw_t r3 = graw<HPL>(Xo + (size_t)u3 * D);
    raw_acc<HPL>(acc, r0); raw_acc<HPL>(acc, r1);
    raw_acc<HPL>(acc, r2); raw_acc<HPL>(acc, r3);
  }
  for (; e < end; ++e) {
    raw_acc<HPL>(acc, graw<HPL>(Xo + (size_t)csr_src[e] * D));
  }

  const float sc = nd[v];
  float o[HPL];
#pragma unroll
  for (int i = 0; i < HPL; ++i) {
    o[i] = sc * acc[i];
    if (BIAS) o[i] += bias[off + i];
  }
  float* yp = Y + (size_t)v * D + off;
  if constexpr (HPL == 4) *reinterpret_cast<float4*>(yp) = make_float4(o[0], o[1], o[2], o[3]);
  else if constexpr (HPL == 2) *reinterpret_cast<float2*>(yp) = make_float2(o[0], o[1]);
  else *yp = o[0];
}

// ---------------- split-bf16 MFMA GEMM ----------------
// C[M][NOUT] = op( A[M][K] @ W[K][NOUT] (+bias) ) [* ns[row] if NSOUT]
// via A_hi*W_hi + A_hi*W_lo + A_lo*W_hi with mfma_f32_16x16x32_bf16.
// AHALF: A is fp16 (exact into hi+lo).  OHALF: C written as fp16.
template <int K, int NOUT, int BM, int WM, int WN, int MF, int NF,
          bool RELU, bool BIAS, bool NSOUT, bool AHALF, bool OHALF>
__global__ __launch_bounds__(256) void k_gemm_mfma(
    const void* __restrict__ A,
    const unsigned short* __restrict__ Wt_hi, const unsigned short* __restrict__ Wt_lo,
    const float* __restrict__ bias, const float* __restrict__ ns,
    void* __restrict__ C, int M) {
  constexpr int BN = WN * NF * 16;
  static_assert(BM == WM * MF * 16, "BM mismatch");
  static_assert(BN == NOUT, "BN must equal NOUT");
  constexpr int LDP = 40;  // 80B row stride -> bank stride 20 -> <=2-way (free), 16B aligned

  __shared__ unsigned short As[2][BM][LDP];   // [hi/lo][row][k]
  __shared__ unsigned short Ws[2][BN][LDP];   // [hi/lo][col][k]

  const int tid = threadIdx.x;
  const int bm = blockIdx.x * BM;
  const int lane = tid & 63;
  const int wave = tid >> 6;
  const int wmi = wave / WN;
  const int wni = wave % WN;
  const int rl = lane & 15;
  const int kg = lane >> 4;       // 0..3
  const int kb = kg * 8;

  f32x4 acc[MF][NF];
#pragma unroll
  for (int m = 0; m < MF; ++m)
#pragma unroll
    for (int n = 0; n < NF; ++n) acc[m][n] = (f32x4){0.f, 0.f, 0.f, 0.f};

  for (int kk = 0; kk < K; kk += 32) {
    // ---- stage A tile (BM x 32), split into hi/lo bf16 ----
#pragma unroll
    for (int s0 = 0; s0 < BM * 8; s0 += 256) {
      int s = s0 + tid;
      int r = s >> 3, c4 = (s & 7) << 2;
      int grow = bm + r;
      float4 v = make_float4(0.f, 0.f, 0.f, 0.f);
      if (grow < M) {
        if constexpr (AHALF) {
          const __half* Ah = reinterpret_cast<const __half*>(A);
          uint2 raw = *reinterpret_cast<const uint2*>(Ah + (size_t)grow * K + kk + c4);
          union { unsigned u; __half2 h; } a, b;
          a.u = raw.x; b.u = raw.y;
          float2 f0 = __half22float2(a.h), f1 = __half22float2(b.h);
          v = make_float4(f0.x, f0.y, f1.x, f1.y);
        } else {
          v = *reinterpret_cast<const float4*>(
              reinterpret_cast<const float*>(A) + (size_t)grow * K + kk + c4);
        }
      }
      ushort4v hi, lo;
      hi[0] = f2bf(v.x); lo[0] = f2bf(v.x - bf2f(hi[0]));
      hi[1] = f2bf(v.y); lo[1] = f2bf(v.y - bf2f(hi[1]));
      hi[2] = f2bf(v.z); lo[2] = f2bf(v.z - bf2f(hi[2]));
      hi[3] = f2bf(v.w); lo[3] = f2bf(v.w - bf2f(hi[3]));
      *reinterpret_cast<ushort4v*>(&As[0][r][c4]) = hi;
      *reinterpret_cast<ushort4v*>(&As[1][r][c4]) = lo;
    }
    // ---- stage W tile (BN cols x 32 k), bf16, pre-transposed ----
#pragma unroll
    for (int s0 = 0; s0 < BN * 4; s0 += 256) {
      int s = s0 + tid;
      int n = s >> 2, k8 = (s & 3) << 3;
      *reinterpret_cast<ushort8v*>(&Ws[0][n][k8]) =
          *reinterpret_cast<const ushort8v*>(Wt_hi + (size_t)n * K + kk + k8);
      *reinterpret_cast<ushort8v*>(&Ws[1][n][k8]) =
          *reinterpret_cast<const ushort8v*>(Wt_lo + (size_t)n * K + kk + k8);
    }
    __syncthreads();

    bf16x8 af[2][MF], bfr[2][NF];
#pragma unroll
    for (int m = 0; m < MF; ++m) {
      const int r = wmi * MF * 16 + m * 16 + rl;
      af[0][m] = *reinterpret_cast<const bf16x8*>(&As[0][r][kb]);
      af[1][m] = *reinterpret_cast<const bf16x8*>(&As[1][r][kb]);
    }
#pragma unroll
    for (int n = 0; n < NF; ++n) {
      const int c = wni * NF * 16 + n * 16 + rl;
      bfr[0][n] = *reinterpret_cast<const bf16x8*>(&Ws[0][c][kb]);
      bfr[1][n] = *reinterpret_cast<const bf16x8*>(&Ws[1][c][kb]);
    }
#pragma unroll
    for (int m = 0; m < MF; ++m)
#pragma unroll
      for (int n = 0; n < NF; ++n) {
        acc[m][n] = __builtin_amdgcn_mfma_f32_16x16x32_bf16(af[0][m], bfr[0][n], acc[m][n], 0, 0, 0);
        acc[m][n] = __builtin_amdgcn_mfma_f32_16x16x32_bf16(af[0][m], bfr[1][n], acc[m][n], 0, 0, 0);
        acc[m][n] = __builtin_amdgcn_mfma_f32_16x16x32_bf16(af[1][m], bfr[0][n], acc[m][n], 0, 0, 0);
      }
    __syncthreads();
  }

  // ---- epilogue ----
#pragma unroll
  for (int m = 0; m < MF; ++m) {
#pragma unroll
    for (int n = 0; n < NF; ++n) {
      const int col = wni * NF * 16 + n * 16 + rl;
      const float bb = BIAS ? bias[col] : 0.f;
      const int rowbase = bm + wmi * MF * 16 + m * 16 + kg * 4;
#pragma unroll
      for (int i = 0; i < 4; ++i) {
        int grow = rowbase + i;
        if (grow < M) {
          float val = acc[m][n][i] + bb;
          if (RELU) val = fmaxf(val, 0.f);
          if (NSOUT) val *= ns[grow];
          if constexpr (OHALF)
            reinterpret_cast<__half*>(C)[(size_t)grow * NOUT + col] = __float2half_rn(val);
          else
            reinterpret_cast<float*>(C)[(size_t)grow * NOUT + col] = val;
        }
      }
    }
  }
}

// ---------------- launch ----------------
extern "C" void kernel_launch(void* const* d_in, const int* in_sizes, int n_in,
                              void* d_out, int out_size, void* d_ws, size_t ws_size,
                              hipStream_t stream) {
  const float* feats = (const float*)d_in[0];
  const float* W1 = (const float*)d_in[1];
  const float* b1 = (const float*)d_in[2];
  const float* W2 = (const float*)d_in[3];
  const float* b2 = (const float*)d_in[4];
  const float* W3 = (const float*)d_in[5];
  const float* b3 = (const float*)d_in[6];
  const int* src = (const int*)d_in[7];
  const int* dst = (const int*)d_in[8];
  float* out = (float*)d_out;
  const int N = NODES;
  const int E = in_sizes[7];
  const int NB = (N + 255) / 256;   // scan blocks (196 <= 256)

  char* ws = (char*)d_ws;
  size_t off = 0;
  auto alloc = [&](size_t bytes) -> void* {
    void* p = ws + off;
    off += (bytes + 255) & ~(size_t)255;
    return p;
  };
  // W0: f32 N*256 (spmm2 out)
  // W1r: f32 N*128 (spmm1 out) then fp16 N*256 (gemm2 out)
  // W2r: fp16: prescaled feats (N*128) -> gemm1 out (N*256) -> gemm3 out (N*64)
  float* w0 = (float*)alloc((size_t)N * 256 * sizeof(float));
  void* w1r = alloc((size_t)N * 128 * sizeof(float));
  __half* w2r = (__half*)alloc((size_t)N * 256 * sizeof(__half));
  int* deg_out = (int*)alloc((size_t)N * sizeof(int));
  int* deg_in = (int*)alloc((size_t)N * sizeof(int));
  int* cursor = (int*)alloc((size_t)N * sizeof(int));
  float* ns = (float*)alloc((size_t)N * sizeof(float));
  float* nd = (float*)alloc((size_t)N * sizeof(float));
  int* row_ptr = (int*)alloc((size_t)(N + 1) * sizeof(int));
  int* csr_src = (int*)alloc((size_t)E * sizeof(int));
  int* psum = (int*)alloc((size_t)NB * sizeof(int));
  unsigned short* w1hi = (unsigned short*)alloc((size_t)F_IN * F_H1 * 2);
  unsigned short* w1lo = (unsigned short*)alloc((size_t)F_IN * F_H1 * 2);
  unsigned short* w2hi = (unsigned short*)alloc((size_t)F_H1 * F_H2 * 2);
  unsigned short* w2lo = (unsigned short*)alloc((size_t)F_H1 * F_H2 * 2);
  unsigned short* w3hi = (unsigned short*)alloc((size_t)F_H2 * F_OUT * 2);
  unsigned short* w3lo = (unsigned short*)alloc((size_t)F_H2 * F_OUT * 2);
  (void)ws_size; (void)n_in; (void)out_size;

  // ---- weight split/transpose (tiny) ----
  hipLaunchKernelGGL(k_wprep, dim3((F_IN * F_H1 + 255) / 256), dim3(256), 0, stream,
                     W1, w1hi, w1lo, F_IN, F_H1);
  hipLaunchKernelGGL(k_wprep, dim3((F_H1 * F_H2 + 255) / 256), dim3(256), 0, stream,
                     W2, w2hi, w2lo, F_H1, F_H2);
  hipLaunchKernelGGL(k_wprep, dim3((F_H2 * F_OUT + 255) / 256), dim3(256), 0, stream,
                     W3, w3hi, w3lo, F_H2, F_OUT);

  // ---- graph preprocessing ----
  hipLaunchKernelGGL(k_init, dim3((N + 255) / 256), dim3(256), 0, stream,
                     deg_out, deg_in, cursor, N);
  hipLaunchKernelGGL(k_count, dim3((E + 255) / 256), dim3(256), 0, stream,
                     src, dst, deg_out, deg_in, E);
  hipLaunchKernelGGL(k_norm, dim3((N + 255) / 256), dim3(256), 0, stream,
                     deg_out, deg_in, ns, nd, N);
  hipLaunchKernelGGL(k_scan1, dim3(NB), dim3(256), 0, stream, deg_in, psum, N);
  hipLaunchKernelGGL(k_scan2, dim3(1), dim3(256), 0, stream, psum, NB);
  hipLaunchKernelGGL(k_scan3, dim3(NB), dim3(256), 0, stream, deg_in, psum, row_ptr, N);
  hipLaunchKernelGGL(k_scatter, dim3((E + 255) / 256), dim3(256), 0, stream,
                     src, dst, row_ptr, cursor, csr_src, E);

  // ---- prescale feats by ns -> fp16 ----
  hipLaunchKernelGGL(k_prescale_h, dim3((N * 32 + 255) / 256), dim3(256), 0, stream,
                     feats, ns, w2r, N * 32);

  auto grid_w = [](int waves) { return dim3((waves + 3) / 4); };  // 4 waves/block

  // ---- layer 1: SpMM(d=128, 2 waves/node, fp16) -> f32; GEMM 128->256 (+b1, relu, *ns) -> fp16
  hipLaunchKernelGGL((k_spmm_h<128, 2, false>), grid_w(N * 2), dim3(256), 0, stream,
                     w2r, row_ptr, csr_src, nd, nullptr, (float*)w1r, N);
  hipLaunchKernelGGL((k_gemm_mfma<128, 256, 64, 1, 4, 4, 4, true, true, true, false, true>),
                     dim3((N + 63) / 64), dim3(256), 0, stream,
                     w1r, w1hi, w1lo, b1, ns, w2r, N);

  // ---- layer 2: SpMM(d=256, 2 waves/node, fp16) -> f32; GEMM 256->256 (+b2, relu, *ns) -> fp16
  hipLaunchKernelGGL((k_spmm_h<256, 2, false>), grid_w(N * 2), dim3(256), 0, stream,
                     w2r, row_ptr, csr_src, nd, nullptr, w0, N);
  hipLaunchKernelGGL((k_gemm_mfma<256, 256, 64, 1, 4, 4, 4, true, true, true, false, true>),
                     dim3((N + 63) / 64), dim3(256), 0, stream,
                     w0, w2hi, w2lo, b2, ns, (__half*)w1r, N);

  // ---- layer 3: GEMM 256->64 (fp16 A, no act) -> fp16; SpMM(d=64, fp16) +b3 -> out f32
  hipLaunchKernelGGL((k_gemm_mfma<256, 64, 128, 4, 1, 2, 4, false, false, false, true, true>),
                     dim3((N + 127) / 128), dim3(256), 0, stream,
                     w1r, w3hi, w3lo, nullptr, nullptr, w2r, N);
  hipLaunchKernelGGL((k_spmm_h<64, 1, true>), grid_w(N), dim3(256), 0, stream,
                     w2r, row_ptr, csr_src, nd, b3, out, N);
}

// Round 6
// 342.112 us; speedup vs baseline: 1.5859x; 1.2135x over previous
//
#include <hip/hip_runtime.h>
#include <hip/hip_fp16.h>
#include <stdint.h>

// ---------------- problem constants ----------------
#define NODES 50000
#define F_IN 128
#define F_H1 256
#define F_H2 256
#define F_OUT 64

using f32x4    = __attribute__((ext_vector_type(4))) float;
using f16x8    = __attribute__((ext_vector_type(8))) _Float16;   // 8 fp16 in 4 VGPRs
using ushort8v = __attribute__((ext_vector_type(8))) unsigned short;

// ---------------- degree / CSR build ----------------
__global__ void k_init(int* deg_out, int* deg_in, int* cursor, int n) {
  int i = blockIdx.x * blockDim.x + threadIdx.x;
  if (i < n) { deg_out[i] = 1; deg_in[i] = 1; cursor[i] = 0; }  // self-loop counts as 1
}

__global__ void k_count(const int* __restrict__ src, const int* __restrict__ dst,
                        int* deg_out, int* deg_in, int e) {
  int i = blockIdx.x * blockDim.x + threadIdx.x;
  if (i < e) {
    atomicAdd(&deg_out[src[i]], 1);
    atomicAdd(&deg_in[dst[i]], 1);
  }
}

__global__ void k_norm(const int* __restrict__ deg_out, const int* __restrict__ deg_in,
                       float* ns, float* nd, int n) {
  int i = blockIdx.x * blockDim.x + threadIdx.x;
  if (i < n) {
    ns[i] = rsqrtf((float)deg_out[i]);
    nd[i] = rsqrtf((float)deg_in[i]);
  }
}

// ---------------- parallel 3-phase exclusive scan over (deg_in - 1) ----------------
__global__ __launch_bounds__(256) void k_scan1(const int* __restrict__ deg_in,
                                               int* __restrict__ psum, int n) {
  int i = blockIdx.x * 256 + threadIdx.x;
  int v = (i < n) ? deg_in[i] - 1 : 0;
#pragma unroll
  for (int o = 1; o < 64; o <<= 1) v += __shfl_xor(v, o);
  __shared__ int ws[4];
  if ((threadIdx.x & 63) == 0) ws[threadIdx.x >> 6] = v;
  __syncthreads();
  if (threadIdx.x == 0) psum[blockIdx.x] = ws[0] + ws[1] + ws[2] + ws[3];
}

__global__ __launch_bounds__(256) void k_scan2(int* __restrict__ psum, int nb) {
  __shared__ int s[256];
  int t = threadIdx.x;
  int v = (t < nb) ? psum[t] : 0;
  s[t] = v;
  __syncthreads();
  for (int o = 1; o < 256; o <<= 1) {
    int u = (t >= o) ? s[t - o] : 0;
    __syncthreads();
    s[t] += u;
    __syncthreads();
  }
  if (t < nb) psum[t] = s[t] - v;   // exclusive
}

__global__ __launch_bounds__(256) void k_scan3(const int* __restrict__ deg_in,
                                               const int* __restrict__ psum,
                                               int* __restrict__ row_ptr, int n) {
  int i = blockIdx.x * 256 + threadIdx.x;
  int lane = threadIdx.x & 63;
  int w = threadIdx.x >> 6;
  int v = (i < n) ? deg_in[i] - 1 : 0;
  int x = v;
#pragma unroll
  for (int o = 1; o < 64; o <<= 1) {
    int u = __shfl_up(x, o);
    if (lane >= o) x += u;
  }
  __shared__ int wsum[4];
  if (lane == 63) wsum[w] = x;
  __syncthreads();
  int woff = 0;
#pragma unroll
  for (int j = 0; j < 4; ++j)
    if (j < w) woff += wsum[j];
  int excl = x - v + woff + psum[blockIdx.x];
  if (i < n) row_ptr[i] = excl;
  if (i == n - 1) row_ptr[n] = excl + v;
}

__global__ void k_scatter(const int* __restrict__ src, const int* __restrict__ dst,
                          const int* __restrict__ row_ptr, int* cursor,
                          int* __restrict__ csr_src, int e) {
  int i = blockIdx.x * blockDim.x + threadIdx.x;
  if (i < e) {
    int d = dst[i];
    int pos = row_ptr[d] + atomicAdd(&cursor[d], 1);
    csr_src[pos] = src[i];
  }
}

// ---------------- feats prescale -> fp16: Y = fp16(ns[row] * X), X:[n][128] ----------------
__global__ void k_prescale_h(const float* __restrict__ X, const float* __restrict__ ns,
                             __half* __restrict__ Y, int total4) {
  int i = blockIdx.x * blockDim.x + threadIdx.x;
  if (i < total4) {
    int row = i >> 5;                       // 32 float4 per 128-col row
    float s = ns[row];
    float4 v = reinterpret_cast<const float4*>(X)[i];
    __half2 h0 = __floats2half2_rn(v.x * s, v.y * s);
    __half2 h1 = __floats2half2_rn(v.z * s, v.w * s);
    union { struct { __half2 a, b; } h; uint2 u; } o;
    o.h.a = h0; o.h.b = h1;
    reinterpret_cast<uint2*>(Y)[i] = o.u;
  }
}

// ---------------- weight prep: W[K][NOUT] f32 -> Wt [NOUT][K] fp16 ----------------
__global__ void k_wprep_h(const float* __restrict__ W, __half* __restrict__ Wt,
                          int K, int NOUT) {
  int i = blockIdx.x * blockDim.x + threadIdx.x;
  if (i < K * NOUT) {
    int k = i / NOUT, n = i % NOUT;
    Wt[(size_t)n * K + k] = __float2half_rn(W[i]);
  }
}

// ---------------- fp16 gather helpers ----------------
template <int HPL> struct raw_t_sel;
template <> struct raw_t_sel<1> { using type = unsigned short; };
template <> struct raw_t_sel<2> { using type = unsigned int; };
template <> struct raw_t_sel<4> { using type = uint2; };

template <int HPL>
__device__ __forceinline__ typename raw_t_sel<HPL>::type graw(const __half* p) {
  return *reinterpret_cast<const typename raw_t_sel<HPL>::type*>(p);
}
template <int HPL>
__device__ __forceinline__ void raw_acc(float* acc, typename raw_t_sel<HPL>::type r) {
  if constexpr (HPL == 4) {
    union { unsigned u; __half2 h; } a, b;
    a.u = r.x; b.u = r.y;
    float2 f0 = __half22float2(a.h), f1 = __half22float2(b.h);
    acc[0] += f0.x; acc[1] += f0.y; acc[2] += f1.x; acc[3] += f1.y;
  } else if constexpr (HPL == 2) {
    union { unsigned u; __half2 h; } a; a.u = r;
    float2 f0 = __half22float2(a.h);
    acc[0] += f0.x; acc[1] += f0.y;
  } else {
    union { unsigned short u; __half h; } a; a.u = r;
    acc[0] += __half2float(a.h);
  }
}

// ---------------- SpMM (fp16 source): Y[v] = nd[v]*(X[v] + sum_{u->v} X[u]) (+bias)
// WPN waves per node (disjoint feature parts); HPL halves per lane. OHALF: fp16 out.
template <int D, int WPN, bool BIAS, bool OHALF>
__global__ __launch_bounds__(256) void k_spmm_h(
    const __half* __restrict__ X, const int* __restrict__ row_ptr,
    const int* __restrict__ csr_src, const float* __restrict__ nd,
    const float* __restrict__ bias, void* __restrict__ Y, int n) {
  constexpr int HPL = D / (64 * WPN);
  static_assert(HPL >= 1 && HPL <= 4, "bad HPL");
  using raw_t = typename raw_t_sel<HPL>::type;
  const int gw = (blockIdx.x * blockDim.x + threadIdx.x) >> 6;
  const int lane = threadIdx.x & 63;
  const int v = (WPN == 2) ? (gw >> 1) : gw;
  const int part = (WPN == 2) ? (gw & 1) : 0;
  if (v >= n) return;
  const int off = part * 64 * HPL + lane * HPL;
  const __half* __restrict__ Xo = X + off;

  float acc[HPL] = {};
  raw_acc<HPL>(acc, graw<HPL>(Xo + (size_t)v * D));   // self term

  const int end = row_ptr[v + 1];
  int e = row_ptr[v];
  for (; e + 4 <= end; e += 4) {
    int u0 = csr_src[e + 0], u1 = csr_src[e + 1];
    int u2 = csr_src[e + 2], u3 = csr_src[e + 3];
    raw_t r0 = graw<HPL>(Xo + (size_t)u0 * D);
    raw_t r1 = graw<HPL>(Xo + (size_t)u1 * D);
    raw_t r2 = graw<HPL>(Xo + (size_t)u2 * D);
    raw_t r3 = graw<HPL>(Xo + (size_t)u3 * D);
    raw_acc<HPL>(acc, r0); raw_acc<HPL>(acc, r1);
    raw_acc<HPL>(acc, r2); raw_acc<HPL>(acc, r3);
  }
  for (; e < end; ++e) {
    raw_acc<HPL>(acc, graw<HPL>(Xo + (size_t)csr_src[e] * D));
  }

  const float sc = nd[v];
  float o[HPL];
#pragma unroll
  for (int i = 0; i < HPL; ++i) {
    o[i] = sc * acc[i];
    if (BIAS) o[i] += bias[off + i];
  }

  if constexpr (OHALF) {
    __half* yp = reinterpret_cast<__half*>(Y) + (size_t)v * D + off;
    if constexpr (HPL == 4) {
      union { struct { __half2 a, b; } h; uint2 u; } pk;
      pk.h.a = __floats2half2_rn(o[0], o[1]);
      pk.h.b = __floats2half2_rn(o[2], o[3]);
      *reinterpret_cast<uint2*>(yp) = pk.u;
    } else if constexpr (HPL == 2) {
      *reinterpret_cast<__half2*>(yp) = __floats2half2_rn(o[0], o[1]);
    } else {
      *yp = __float2half_rn(o[0]);
    }
  } else {
    float* yp = reinterpret_cast<float*>(Y) + (size_t)v * D + off;
    if constexpr (HPL == 4) *reinterpret_cast<float4*>(yp) = make_float4(o[0], o[1], o[2], o[3]);
    else if constexpr (HPL == 2) *reinterpret_cast<float2*>(yp) = make_float2(o[0], o[1]);
    else *yp = o[0];
  }
}

// ---------------- pure-fp16 MFMA GEMM ----------------
// C[M][NOUT] = op( A[M][K] @ W[K][NOUT] (+bias) ) [* ns[row] if NSOUT]
// A fp16 row-major; Wt fp16 pre-transposed [NOUT][K]; f32 accumulate via
// mfma_f32_16x16x32_f16.  OHALF: C written as fp16, else f32.
// A-frag: row = lane&15, k = (lane>>4)*8 + j;  B-frag: col = lane&15, same k.
// C/D:    col = lane&15, row = (lane>>4)*4 + reg   [dtype-independent, m89/m121]
template <int K, int NOUT, int BM, int WM, int WN, int MF, int NF,
          bool RELU, bool BIAS, bool NSOUT, bool OHALF>
__global__ __launch_bounds__(256) void k_gemm_h(
    const __half* __restrict__ A, const __half* __restrict__ Wt,
    const float* __restrict__ bias, const float* __restrict__ ns,
    void* __restrict__ C, int M) {
  constexpr int BN = WN * NF * 16;
  static_assert(BM == WM * MF * 16, "BM mismatch");
  static_assert(BN == NOUT, "BN must equal NOUT");
  constexpr int LDP = 40;  // 80B row stride -> bank stride 20 -> <=2-way (free), 16B aligned

  __shared__ __half As[BM][LDP];
  __shared__ __half Ws[BN][LDP];

  const int tid = threadIdx.x;
  const int bm = blockIdx.x * BM;
  const int lane = tid & 63;
  const int wave = tid >> 6;
  const int wmi = wave / WN;
  const int wni = wave % WN;
  const int rl = lane & 15;
  const int kg = lane >> 4;       // 0..3
  const int kb = kg * 8;

  f32x4 acc[MF][NF];
#pragma unroll
  for (int m = 0; m < MF; ++m)
#pragma unroll
    for (int n = 0; n < NF; ++n) acc[m][n] = (f32x4){0.f, 0.f, 0.f, 0.f};

  for (int kk = 0; kk < K; kk += 32) {
    // ---- stage A tile (BM x 32 fp16): ushort8 per slot ----
#pragma unroll
    for (int s0 = 0; s0 < BM * 4; s0 += 256) {
      int s = s0 + tid;
      int r = s >> 2, c8 = (s & 3) << 3;
      int grow = bm + r;
      ushort8v v = (ushort8v){0, 0, 0, 0, 0, 0, 0, 0};
      if (grow < M)
        v = *reinterpret_cast<const ushort8v*>(A + (size_t)grow * K + kk + c8);
      *reinterpret_cast<ushort8v*>(&As[r][c8]) = v;
    }
    // ---- stage W tile (BN cols x 32 k) ----
#pragma unroll
    for (int s0 = 0; s0 < BN * 4; s0 += 256) {
      int s = s0 + tid;
      int nn = s >> 2, k8 = (s & 3) << 3;
      *reinterpret_cast<ushort8v*>(&Ws[nn][k8]) =
          *reinterpret_cast<const ushort8v*>(Wt + (size_t)nn * K + kk + k8);
    }
    __syncthreads();

    f16x8 af[MF], bf[NF];
#pragma unroll
    for (int m = 0; m < MF; ++m) {
      const int r = wmi * MF * 16 + m * 16 + rl;
      af[m] = *reinterpret_cast<const f16x8*>(&As[r][kb]);
    }
#pragma unroll
    for (int n = 0; n < NF; ++n) {
      const int c = wni * NF * 16 + n * 16 + rl;
      bf[n] = *reinterpret_cast<const f16x8*>(&Ws[c][kb]);
    }
#pragma unroll
    for (int m = 0; m < MF; ++m)
#pragma unroll
      for (int n = 0; n < NF; ++n)
        acc[m][n] = __builtin_amdgcn_mfma_f32_16x16x32_f16(af[m], bf[n], acc[m][n], 0, 0, 0);
    __syncthreads();
  }

  // ---- epilogue ----
#pragma unroll
  for (int m = 0; m < MF; ++m) {
#pragma unroll
    for (int n = 0; n < NF; ++n) {
      const int col = wni * NF * 16 + n * 16 + rl;
      const float bb = BIAS ? bias[col] : 0.f;
      const int rowbase = bm + wmi * MF * 16 + m * 16 + kg * 4;
#pragma unroll
      for (int i = 0; i < 4; ++i) {
        int grow = rowbase + i;
        if (grow < M) {
          float val = acc[m][n][i] + bb;
          if (RELU) val = fmaxf(val, 0.f);
          if (NSOUT) val *= ns[grow];
          if constexpr (OHALF)
            reinterpret_cast<__half*>(C)[(size_t)grow * NOUT + col] = __float2half_rn(val);
          else
            reinterpret_cast<float*>(C)[(size_t)grow * NOUT + col] = val;
        }
      }
    }
  }
}

// ---------------- launch ----------------
extern "C" void kernel_launch(void* const* d_in, const int* in_sizes, int n_in,
                              void* d_out, int out_size, void* d_ws, size_t ws_size,
                              hipStream_t stream) {
  const float* feats = (const float*)d_in[0];
  const float* W1 = (const float*)d_in[1];
  const float* b1 = (const float*)d_in[2];
  const float* W2 = (const float*)d_in[3];
  const float* b2 = (const float*)d_in[4];
  const float* W3 = (const float*)d_in[5];
  const float* b3 = (const float*)d_in[6];
  const int* src = (const int*)d_in[7];
  const int* dst = (const int*)d_in[8];
  float* out = (float*)d_out;
  const int N = NODES;
  const int E = in_sizes[7];
  const int NB = (N + 255) / 256;   // scan blocks (196 <= 256)

  char* ws = (char*)d_ws;
  size_t off = 0;
  auto alloc = [&](size_t bytes) -> void* {
    void* p = ws + off;
    off += (bytes + 255) & ~(size_t)255;
    return p;
  };
  // All activation buffers fp16 N*256:
  // w2r: prescaled feats (N*128) -> gemm1 out (N*256) -> gemm3 out (N*64)
  // w1r: spmm1 out (N*128) -> gemm2 out (N*256)
  // w0h: spmm2 out (N*256)
  __half* w0h = (__half*)alloc((size_t)N * 256 * sizeof(__half));
  __half* w1r = (__half*)alloc((size_t)N * 256 * sizeof(__half));
  __half* w2r = (__half*)alloc((size_t)N * 256 * sizeof(__half));
  int* deg_out = (int*)alloc((size_t)N * sizeof(int));
  int* deg_in = (int*)alloc((size_t)N * sizeof(int));
  int* cursor = (int*)alloc((size_t)N * sizeof(int));
  float* ns = (float*)alloc((size_t)N * sizeof(float));
  float* nd = (float*)alloc((size_t)N * sizeof(float));
  int* row_ptr = (int*)alloc((size_t)(N + 1) * sizeof(int));
  int* csr_src = (int*)alloc((size_t)E * sizeof(int));
  int* psum = (int*)alloc((size_t)NB * sizeof(int));
  __half* wt1 = (__half*)alloc((size_t)F_IN * F_H1 * sizeof(__half));
  __half* wt2 = (__half*)alloc((size_t)F_H1 * F_H2 * sizeof(__half));
  __half* wt3 = (__half*)alloc((size_t)F_H2 * F_OUT * sizeof(__half));
  (void)ws_size; (void)n_in; (void)out_size;

  // ---- weight transpose -> fp16 (tiny) ----
  hipLaunchKernelGGL(k_wprep_h, dim3((F_IN * F_H1 + 255) / 256), dim3(256), 0, stream,
                     W1, wt1, F_IN, F_H1);
  hipLaunchKernelGGL(k_wprep_h, dim3((F_H1 * F_H2 + 255) / 256), dim3(256), 0, stream,
                     W2, wt2, F_H1, F_H2);
  hipLaunchKernelGGL(k_wprep_h, dim3((F_H2 * F_OUT + 255) / 256), dim3(256), 0, stream,
                     W3, wt3, F_H2, F_OUT);

  // ---- graph preprocessing ----
  hipLaunchKernelGGL(k_init, dim3((N + 255) / 256), dim3(256), 0, stream,
                     deg_out, deg_in, cursor, N);
  hipLaunchKernelGGL(k_count, dim3((E + 255) / 256), dim3(256), 0, stream,
                     src, dst, deg_out, deg_in, E);
  hipLaunchKernelGGL(k_norm, dim3((N + 255) / 256), dim3(256), 0, stream,
                     deg_out, deg_in, ns, nd, N);
  hipLaunchKernelGGL(k_scan1, dim3(NB), dim3(256), 0, stream, deg_in, psum, N);
  hipLaunchKernelGGL(k_scan2, dim3(1), dim3(256), 0, stream, psum, NB);
  hipLaunchKernelGGL(k_scan3, dim3(NB), dim3(256), 0, stream, deg_in, psum, row_ptr, N);
  hipLaunchKernelGGL(k_scatter, dim3((E + 255) / 256), dim3(256), 0, stream,
                     src, dst, row_ptr, cursor, csr_src, E);

  // ---- prescale feats by ns -> fp16 ----
  hipLaunchKernelGGL(k_prescale_h, dim3((N * 32 + 255) / 256), dim3(256), 0, stream,
                     feats, ns, w2r, N * 32);

  auto grid_w = [](int waves) { return dim3((waves + 3) / 4); };  // 4 waves/block

  // ---- layer 1: SpMM(d=128, 1 wave/node) -> fp16; GEMM 128->256 (+b1, relu, *ns) -> fp16
  hipLaunchKernelGGL((k_spmm_h<128, 1, false, true>), grid_w(N), dim3(256), 0, stream,
                     w2r, row_ptr, csr_src, nd, nullptr, w1r, N);
  hipLaunchKernelGGL((k_gemm_h<128, 256, 64, 1, 4, 4, 4, true, true, true, true>),
                     dim3((N + 63) / 64), dim3(256), 0, stream,
                     w1r, wt1, b1, ns, w2r, N);

  // ---- layer 2: SpMM(d=256, 1 wave/node) -> fp16; GEMM 256->256 (+b2, relu, *ns) -> fp16
  hipLaunchKernelGGL((k_spmm_h<256, 1, false, true>), grid_w(N), dim3(256), 0, stream,
                     w2r, row_ptr, csr_src, nd, nullptr, w0h, N);
  hipLaunchKernelGGL((k_gemm_h<256, 256, 64, 1, 4, 4, 4, true, true, true, true>),
                     dim3((N + 63) / 64), dim3(256), 0, stream,
                     w0h, wt2, b2, ns, w1r, N);

  // ---- layer 3: GEMM 256->64 (no act) -> fp16; SpMM(d=64) +b3 -> out f32
  hipLaunchKernelGGL((k_gemm_h<256, 64, 128, 4, 1, 2, 4, false, false, false, true>),
                     dim3((N + 127) / 128), dim3(256), 0, stream,
                     w1r, wt3, nullptr, nullptr, w2r, N);
  hipLaunchKernelGGL((k_spmm_h<64, 1, true, false>), grid_w(N), dim3(256), 0, stream,
                     w2r, row_ptr, csr_src, nd, b3, out, N);
}